// Round 6
// baseline (270.570 us; speedup 1.0000x reference)
//
#include <hip/hip_runtime.h>
#include <math.h>

#define HH 256
#define WW 256
#define BC 512   // B*C = 8*64
#define QN 100
#define RBAND 16 // output rows per wave

// ---------------------------------------------------------------------------
// Kernel 1: per-(b,c) 18x100 GEMM + q output + derived conv coefficients.
// coef layout per bc (stride 32 floats): [0..8]=former, [9..17]=wk,
// [18..26]=|wk|, [27..29]=column sums of wk (kept for layout compat).
// ---------------------------------------------------------------------------
__global__ __launch_bounds__(128) void prep_kernel(
    const float* __restrict__ query,   // (100, 8, 64) = (100, 512)
    const float* __restrict__ Wl,      // (18, 100)
    const float* __restrict__ bl,      // (18,)
    const float* __restrict__ Wd,      // (100, 18)
    const float* __restrict__ bd,      // (100,)
    float* __restrict__ qout,          // (100, 512) region of d_out
    float* __restrict__ coef)          // (512, 32) in d_ws
{
    const int bc = blockIdx.x;
    const int t  = threadIdx.x;
    __shared__ float qcol[QN];
    __shared__ float c18[18];

    if (t < QN) qcol[t] = query[t * BC + bc];
    __syncthreads();

    if (t < 18) {
        float acc = bl[t];
        const float* wrow = Wl + t * QN;
        #pragma unroll 4
        for (int qi = 0; qi < QN; ++qi) acc += qcol[qi] * wrow[qi];
        c18[t] = acc;
    }
    __syncthreads();

    if (t < QN) {
        float acc = bd[t];
        const float* wrow = Wd + t * 18;
        #pragma unroll
        for (int k = 0; k < 18; ++k) acc += c18[k] * wrow[k];
        qout[t * BC + bc] = acc;   // q.transpose(2,0,1) layout
    }

    if (t < 18) {
        coef[bc * 32 + t] = c18[t];                      // former / wk
    } else if (t < 27) {
        coef[bc * 32 + t] = fabsf(c18[t - 9]);           // |wk|
    } else if (t < 30) {
        int j = t - 27;
        coef[bc * 32 + t] = c18[9 + j] + c18[12 + j] + c18[15 + j]; // colsum
    }
}

// ---------------------------------------------------------------------------
// Kernel 2: LDS-free streaming stencil, DISTANCE-2 software-pipelined loads.
// One wave64 spans the full 256-col image width (4 cols/lane); each wave
// streams a 16-row band.  Register state:
//   v[4][6]   : finished value rows h-1..h+2 (halo cols, edge-masked)
//   raw[2][6] : ping-pong in-flight rows — ISSUE(h+4) at iter j is FINISHed
//               at iter j+2, so the vmcnt wait lands TWO iterations (~600+
//               issue-cycles) after issue: covers L3/HBM latency even when
//               the wave convoy compresses (round-5 post-mortem: distance-1
//               gave VALUBusy 48% with both pipes idle half the time).
//   d[4][6]   : diff rows h-1..h+1
//   yt2[2][4] : former-conv row reuse (COMPD saves yt, OUTROW consumes).
// Column halos fetched as 2 clamped dword loads (same cache lines as the
// neighbors' float4 -> no extra HBM).  Diff halos via 2 shfl per row.
// Iteration j (h = r0+j):  FINISH raw[j&1] (row h+2, issued at j-2)  |
//   ISSUE row h+4 into raw[j&1]  |  COMPD diff(h+1) (+save yt)  |
//   OUTROW(h) (reuses yt(h)).
// ---------------------------------------------------------------------------
__global__ __launch_bounds__(256, 4) void fused_kernel(
    const float* __restrict__ value,   // (512, 256, 256)
    const float* __restrict__ coef,    // (512, 32)
    float* __restrict__ yout)          // (512, 256, 256) region of d_out
{
    const int bc   = blockIdx.z;
    const int wave = threadIdx.x >> 6;
    const int lane = threadIdx.x & 63;
    const int band = blockIdx.x * 4 + wave;
    const int r0   = band * RBAND;
    const int x4   = lane << 2;

    const bool l0  = (lane == 0);
    const bool l63 = (lane == 63);
    // clamped halo columns (stay inside the row; masked to 0 at FINISH)
    const int xl = l0  ? 0   : x4 - 1;
    const int xr = l63 ? 255 : x4 + 4;

    // coefficients: block-uniform address -> scalar (SGPR) loads
    const float* cp = coef + bc * 32;
    float fco[9], awk[9], wk6[6];
    #pragma unroll
    for (int i = 0; i < 9; ++i) { fco[i] = cp[i]; awk[i] = cp[18 + i]; }
    wk6[0] = cp[9];  wk6[1] = cp[10]; wk6[2] = cp[11];
    wk6[3] = cp[15]; wk6[4] = cp[16]; wk6[5] = cp[17];

    const float* vbase = value + (size_t)bc * (HH * WW);
    float*       obase = yout  + (size_t)bc * (HH * WW);

    float v[4][6];
    float raw[2][6];
    float d[4][6];
    float yt2[2][4];

    // tree-form 9-term dot: 3 independent 3-FMA chains, then 2 adds
    auto DOT9 = [](const float* f, const float* ra, const float* rb,
                   const float* rc, int c) -> float {
        float s0 = fmaf(f[2], ra[c + 2], fmaf(f[1], ra[c + 1], f[0] * ra[c]));
        float s1 = fmaf(f[5], rb[c + 2], fmaf(f[4], rb[c + 1], f[3] * rb[c]));
        float s2 = fmaf(f[8], rc[c + 2], fmaf(f[7], rc[c + 1], f[6] * rc[c]));
        return (s0 + s1) + s2;
    };

    // issue row r's loads into rw (no masking, no wait — consumed 2 iters on)
    auto ISSUE = [&](int r, float* rw) {
        if ((unsigned)r < HH) {
            const float* rowp = vbase + r * WW;
            const float4 q = *(const float4*)(rowp + x4);
            rw[0] = rowp[xl];
            rw[1] = q.x; rw[2] = q.y; rw[3] = q.z; rw[4] = q.w;
            rw[5] = rowp[xr];
        } else {
            #pragma unroll
            for (int m = 0; m < 6; ++m) rw[m] = 0.f;
        }
    };

    // edge-mask a raw buffer and retire it into a finished v row
    auto FINISH = [&](const float* rw, float* vr) {
        vr[0] = l0 ? 0.f : rw[0];
        vr[1] = rw[1]; vr[2] = rw[2]; vr[3] = rw[3]; vr[4] = rw[4];
        vr[5] = l63 ? 0.f : rw[5];
    };

    // prologue row load: issue + finish immediately (independent loads batch)
    auto LOADV = [&](int r, float* vr) {
        float tmp[6];
        ISSUE(r, tmp);
        FINISH(tmp, vr);
    };

    // diff row r from value rows r-1 (va), r (vb), r+1 (vc); saves yt(r)
    auto COMPD = [&](int r, const float* va, const float* vb, const float* vc,
                     float* drow, float* ytr) {
        if ((unsigned)r < HH) {
            float d4[4];
            #pragma unroll
            for (int c = 0; c < 4; ++c) {
                float yt = DOT9(fco, va, vb, vc, c);
                ytr[c] = yt;
                float e = vb[c + 1] - yt;
                d4[c] = __expf(-e * e);
            }
            drow[1] = d4[0]; drow[2] = d4[1]; drow[3] = d4[2]; drow[4] = d4[3];
            float left  = __shfl_up(d4[3], 1);
            float right = __shfl_down(d4[0], 1);
            drow[0] = l0  ? 0.f : left;
            drow[5] = l63 ? 0.f : right;
        } else {
            #pragma unroll
            for (int m = 0; m < 6; ++m) drow[m] = 0.f;
        }
    };

    // output row h; yt(h) comes precomputed from COMPD(h) via ytr
    auto OUTROW = [&](int h, const float* vp, const float* vq, const float* vs,
                      const float* dp, const float* dq, const float* ds,
                      const float* ytr) {
        float dv0[6], dv2[6];
        #pragma unroll
        for (int m = 0; m < 6; ++m) {
            float mid = dq[m] * vq[m];
            dv0[m] = fmaf(dp[m], vp[m], -mid);
            dv2[m] = fmaf(ds[m], vs[m], -mid);
        }
        float4 o;
        #pragma unroll
        for (int c = 0; c < 4; ++c) {
            float y0 = fmaf(awk[2], dp[c + 2],
                       fmaf(awk[1], dp[c + 1], fmaf(awk[0], dp[c], 1e-10f)));
            float y1 = fmaf(awk[5], dq[c + 2],
                       fmaf(awk[4], dq[c + 1], awk[3] * dq[c]));
            float y2 = fmaf(awk[8], ds[c + 2],
                       fmaf(awk[7], ds[c + 1], awk[6] * ds[c]));
            float yd9 = (y0 + y1) + y2;
            float n0 = fmaf(wk6[2], dv0[c + 2],
                       fmaf(wk6[1], dv0[c + 1], wk6[0] * dv0[c]));
            float n1 = fmaf(wk6[5], dv2[c + 2],
                       fmaf(wk6[4], dv2[c + 1], wk6[3] * dv2[c]));
            float num = n0 + n1;
            (&o.x)[c] = fmaf(-num, __builtin_amdgcn_rcpf(yd9), ytr[c]);
        }
        *(float4*)(obase + h * WW + x4) = o;
    };

    // ---- prologue: rows r0-2 .. r0+1 finished; diff rows r0-1, r0 (+yt);
    //      rows r0+2 (raw[0]) and r0+3 (raw[1]) in flight ----
    LOADV(r0 - 2, v[0]);
    LOADV(r0 - 1, v[1]);
    LOADV(r0,     v[2]);
    LOADV(r0 + 1, v[3]);
    COMPD(r0 - 1, v[0], v[1], v[2], d[0], yt2[1]);
    COMPD(r0,     v[1], v[2], v[3], d[1], yt2[0]);
    ISSUE(r0 + 2, raw[0]);
    ISSUE(r0 + 3, raw[1]);

    // ---- main loop: RBAND rows, unrolled x4 so all slot indices are static.
    // v slot(r) = (r - r0 + 2) & 3 ; d slot(r) = (r - r0 + 1) & 3 ;
    // yt slot(r) = (r - r0) & 1 ; raw parity(r) = r & parity of (r0+j) etc.
    // j&1 == j4&1 since io is a multiple of 4.
    for (int io = 0; io < RBAND; io += 4) {
        #pragma unroll
        for (int j4 = 0; j4 < 4; ++j4) {
            const int j = io + j4;
            const int h = r0 + j;
            FINISH(raw[j4 & 1], v[j4 & 3]);        // retire row h+2 (issued j-2)
            if (j < RBAND - 2)                      // wave-uniform scalar guard
                ISSUE(h + 4, raw[j4 & 1]);          // two rows ahead in flight
            COMPD(h + 1, v[(j4 + 2) & 3], v[(j4 + 3) & 3], v[j4 & 3],
                  d[(j4 + 2) & 3], yt2[(j + 1) & 1]);
            OUTROW(h, v[(j4 + 1) & 3], v[(j4 + 2) & 3], v[(j4 + 3) & 3],
                   d[j4 & 3], d[(j4 + 1) & 3], d[(j4 + 2) & 3],
                   yt2[j & 1]);
        }
    }
}

// ---------------------------------------------------------------------------
extern "C" void kernel_launch(void* const* d_in, const int* in_sizes, int n_in,
                              void* d_out, int out_size, void* d_ws, size_t ws_size,
                              hipStream_t stream) {
    const float* query = (const float*)d_in[0];   // (100,8,64)
    const float* value = (const float*)d_in[1];   // (8,64,256,256)
    // d_in[2..4]: unused scalars
    const float* Wl    = (const float*)d_in[5];   // (18,100)
    const float* bl    = (const float*)d_in[6];   // (18,)
    const float* Wd    = (const float*)d_in[7];   // (100,18)
    const float* bd    = (const float*)d_in[8];   // (100,)

    float* out   = (float*)d_out;
    float* qout  = out;                 // first 100*512 floats
    float* yout  = out + QN * BC;       // then 512*256*256 floats
    float* coef  = (float*)d_ws;        // 512*32 floats = 64 KB

    prep_kernel<<<BC, 128, 0, stream>>>(query, Wl, bl, Wd, bd, qout, coef);

    // 16 bands of 16 rows per image; 4 waves (bands) per block
    dim3 grid(HH / (RBAND * 4), 1, BC);
    fused_kernel<<<grid, 256, 0, stream>>>(value, coef, yout);
}

// Round 7
// 269.195 us; speedup vs baseline: 1.0051x; 1.0051x over previous
//
#include <hip/hip_runtime.h>
#include <math.h>

#define HH 256
#define WW 256
#define BC 512   // B*C = 8*64
#define QN 100
#define RBAND 16 // output rows per wave

// ---------------------------------------------------------------------------
// Kernel 1: per-(b,c) 18x100 GEMM + q output + derived conv coefficients.
// coef layout per bc (stride 32 floats): [0..8]=former, [9..17]=wk,
// [18..26]=|wk|, [27..29]=column sums of wk (kept for layout compat).
// ---------------------------------------------------------------------------
__global__ __launch_bounds__(128) void prep_kernel(
    const float* __restrict__ query,   // (100, 8, 64) = (100, 512)
    const float* __restrict__ Wl,      // (18, 100)
    const float* __restrict__ bl,      // (18,)
    const float* __restrict__ Wd,      // (100, 18)
    const float* __restrict__ bd,      // (100,)
    float* __restrict__ qout,          // (100, 512) region of d_out
    float* __restrict__ coef)          // (512, 32) in d_ws
{
    const int bc = blockIdx.x;
    const int t  = threadIdx.x;
    __shared__ float qcol[QN];
    __shared__ float c18[18];

    if (t < QN) qcol[t] = query[t * BC + bc];
    __syncthreads();

    if (t < 18) {
        float acc = bl[t];
        const float* wrow = Wl + t * QN;
        #pragma unroll 4
        for (int qi = 0; qi < QN; ++qi) acc += qcol[qi] * wrow[qi];
        c18[t] = acc;
    }
    __syncthreads();

    if (t < QN) {
        float acc = bd[t];
        const float* wrow = Wd + t * 18;
        #pragma unroll
        for (int k = 0; k < 18; ++k) acc += c18[k] * wrow[k];
        qout[t * BC + bc] = acc;   // q.transpose(2,0,1) layout
    }

    if (t < 18) {
        coef[bc * 32 + t] = c18[t];                      // former / wk
    } else if (t < 27) {
        coef[bc * 32 + t] = fabsf(c18[t - 9]);           // |wk|
    } else if (t < 30) {
        int j = t - 27;
        coef[bc * 32 + t] = c18[9 + j] + c18[12 + j] + c18[15 + j]; // colsum
    }
}

// ---------------------------------------------------------------------------
// Kernel 2: LDS-free, SHUFFLE-FREE streaming stencil (DS ops fully removed).
// One wave64 spans the full 256-col image width (4 output cols/lane); each
// wave streams a 16-row band.  Register state:
//   v[4][8]   : value rows h-1..h+2, logical cols x4-2 .. x4+5 (edge-masked).
//               Halo cols fetched as two clamped dwordx2 loads (same cache
//               lines as neighbor lanes' float4 -> no extra HBM traffic).
//   raw[8]    : in-flight row (distance-1; round-6 showed distance-2 neutral)
//   d[4][6]   : diff rows h-1..h+1, logical cols x4-1 .. x4+4 — the halo
//               diffs (cols x4-1, x4+4) are computed REDUNDANTLY in-lane
//               instead of shuffled from neighbors: kills the per-iteration
//               ds_bpermute -> lgkmcnt -> cndmask round-trip that round-6's
//               post-mortem identified as the critical-path serializer.
//   yt2[2][4] : former-conv reuse (COMPD(h) saves yt, OUTROW(h) consumes).
// Iteration j (h = r0+j):  FINISH raw->v (row h+2)  |  ISSUE row h+3  |
//   COMPD diff(h+1) 6-wide (+save yt)  |  OUTROW(h).
// ---------------------------------------------------------------------------
__global__ __launch_bounds__(256, 4) void fused_kernel(
    const float* __restrict__ value,   // (512, 256, 256)
    const float* __restrict__ coef,    // (512, 32)
    float* __restrict__ yout)          // (512, 256, 256) region of d_out
{
    const int bc   = blockIdx.z;
    const int wave = threadIdx.x >> 6;
    const int lane = threadIdx.x & 63;
    const int band = blockIdx.x * 4 + wave;
    const int r0   = band * RBAND;
    const int x4   = lane << 2;

    const bool l0  = (lane == 0);
    const bool l63 = (lane == 63);
    // clamped halo bases (8B/16B aligned; garbage masked at FINISH)
    const int xl = l0  ? 0   : x4 - 2;   // left  halo dwordx2: cols x4-2, x4-1
    const int xr = l63 ? 252 : x4 + 4;   // right halo dwordx2: cols x4+4, x4+5

    // coefficients: block-uniform address -> scalar (SGPR) loads
    const float* cp = coef + bc * 32;
    float fco[9], awk[9], wk6[6];
    #pragma unroll
    for (int i = 0; i < 9; ++i) { fco[i] = cp[i]; awk[i] = cp[18 + i]; }
    wk6[0] = cp[9];  wk6[1] = cp[10]; wk6[2] = cp[11];
    wk6[3] = cp[15]; wk6[4] = cp[16]; wk6[5] = cp[17];

    const float* vbase = value + (size_t)bc * (HH * WW);
    float*       obase = yout  + (size_t)bc * (HH * WW);

    float v[4][8];     // rows: logical col = x4-2+m
    float raw[8];
    float d[4][6];     // rows: logical col = x4-1+k
    float yt2[2][4];

    // tree-form 9-term dot at column offset k: reads ra/rb/rc[k..k+2]
    auto DOT9 = [](const float* f, const float* ra, const float* rb,
                   const float* rc, int k) -> float {
        float s0 = fmaf(f[2], ra[k + 2], fmaf(f[1], ra[k + 1], f[0] * ra[k]));
        float s1 = fmaf(f[5], rb[k + 2], fmaf(f[4], rb[k + 1], f[3] * rb[k]));
        float s2 = fmaf(f[8], rc[k + 2], fmaf(f[7], rc[k + 1], f[6] * rc[k]));
        return (s0 + s1) + s2;
    };

    // issue row r's loads into rw (no masking, no wait — consumed next iter)
    auto ISSUE = [&](int r, float* rw) {
        if ((unsigned)r < HH) {
            const float* rowp = vbase + r * WW;
            const float2 a = *(const float2*)(rowp + xl);
            const float4 q = *(const float4*)(rowp + x4);
            const float2 b = *(const float2*)(rowp + xr);
            rw[0] = a.x; rw[1] = a.y;
            rw[2] = q.x; rw[3] = q.y; rw[4] = q.z; rw[5] = q.w;
            rw[6] = b.x; rw[7] = b.y;
        } else {
            #pragma unroll
            for (int m = 0; m < 8; ++m) rw[m] = 0.f;
        }
    };

    // edge-mask a raw buffer and retire it into a finished v row
    auto FINISH = [&](const float* rw, float* vr) {
        vr[0] = l0 ? 0.f : rw[0];
        vr[1] = l0 ? 0.f : rw[1];
        vr[2] = rw[2]; vr[3] = rw[3]; vr[4] = rw[4]; vr[5] = rw[5];
        vr[6] = l63 ? 0.f : rw[6];
        vr[7] = l63 ? 0.f : rw[7];
    };

    // prologue row load: issue + finish immediately (independent loads batch)
    auto LOADV = [&](int r, float* vr) {
        float tmp[8];
        ISSUE(r, tmp);
        FINISH(tmp, vr);
    };

    // diff row r (6-wide, cols x4-1..x4+4) from value rows r-1/r/r+1 (8-wide);
    // saves yt for the 4 center cols.  No cross-lane ops.
    auto COMPD = [&](int r, const float* va, const float* vb, const float* vc,
                     float* drow, float* ytr) {
        if ((unsigned)r < HH) {
            #pragma unroll
            for (int k = 0; k < 6; ++k) {
                float yt = DOT9(fco, va, vb, vc, k);
                if (k >= 1 && k <= 4) ytr[k - 1] = yt;
                float e = vb[k + 1] - yt;
                drow[k] = __expf(-e * e);
            }
            if (l0)  drow[0] = 0.f;   // image col -1
            if (l63) drow[5] = 0.f;   // image col 256
        } else {
            #pragma unroll
            for (int k = 0; k < 6; ++k) drow[k] = 0.f;
        }
    };

    // output row h; yt(h) comes precomputed from COMPD(h) via ytr.
    // v rows are 8-wide: value col x4-1+m lives at index m+1.
    auto OUTROW = [&](int h, const float* vp, const float* vq, const float* vs,
                      const float* dp, const float* dq, const float* ds,
                      const float* ytr) {
        float dv0[6], dv2[6];
        #pragma unroll
        for (int m = 0; m < 6; ++m) {
            float mid = dq[m] * vq[m + 1];
            dv0[m] = fmaf(dp[m], vp[m + 1], -mid);
            dv2[m] = fmaf(ds[m], vs[m + 1], -mid);
        }
        float4 o;
        #pragma unroll
        for (int c = 0; c < 4; ++c) {
            float y0 = fmaf(awk[2], dp[c + 2],
                       fmaf(awk[1], dp[c + 1], fmaf(awk[0], dp[c], 1e-10f)));
            float y1 = fmaf(awk[5], dq[c + 2],
                       fmaf(awk[4], dq[c + 1], awk[3] * dq[c]));
            float y2 = fmaf(awk[8], ds[c + 2],
                       fmaf(awk[7], ds[c + 1], awk[6] * ds[c]));
            float yd9 = (y0 + y1) + y2;
            float n0 = fmaf(wk6[2], dv0[c + 2],
                       fmaf(wk6[1], dv0[c + 1], wk6[0] * dv0[c]));
            float n1 = fmaf(wk6[5], dv2[c + 2],
                       fmaf(wk6[4], dv2[c + 1], wk6[3] * dv2[c]));
            float num = n0 + n1;
            (&o.x)[c] = fmaf(-num, __builtin_amdgcn_rcpf(yd9), ytr[c]);
        }
        *(float4*)(obase + h * WW + x4) = o;
    };

    // ---- prologue: rows r0-2 .. r0+1 finished; diff rows r0-1, r0 (+yt);
    //      row r0+2 in flight ----
    LOADV(r0 - 2, v[0]);
    LOADV(r0 - 1, v[1]);
    LOADV(r0,     v[2]);
    LOADV(r0 + 1, v[3]);
    COMPD(r0 - 1, v[0], v[1], v[2], d[0], yt2[1]);
    COMPD(r0,     v[1], v[2], v[3], d[1], yt2[0]);
    ISSUE(r0 + 2, raw);

    // ---- main loop: RBAND rows, unrolled x4 so all slot indices are static.
    // v slot(r) = (r - r0 + 2) & 3 ; d slot(r) = (r - r0 + 1) & 3 ;
    // yt slot(r) = (r - r0) & 1.
    for (int io = 0; io < RBAND; io += 4) {
        #pragma unroll
        for (int j4 = 0; j4 < 4; ++j4) {
            const int j = io + j4;
            const int h = r0 + j;
            FINISH(raw, v[j4 & 3]);                // retire row h+2
            ISSUE(h + 3, raw);                     // next row in flight
            COMPD(h + 1, v[(j4 + 2) & 3], v[(j4 + 3) & 3], v[j4 & 3],
                  d[(j4 + 2) & 3], yt2[(j + 1) & 1]);
            OUTROW(h, v[(j4 + 1) & 3], v[(j4 + 2) & 3], v[(j4 + 3) & 3],
                   d[j4 & 3], d[(j4 + 1) & 3], d[(j4 + 2) & 3],
                   yt2[j & 1]);
        }
    }
}

// ---------------------------------------------------------------------------
extern "C" void kernel_launch(void* const* d_in, const int* in_sizes, int n_in,
                              void* d_out, int out_size, void* d_ws, size_t ws_size,
                              hipStream_t stream) {
    const float* query = (const float*)d_in[0];   // (100,8,64)
    const float* value = (const float*)d_in[1];   // (8,64,256,256)
    // d_in[2..4]: unused scalars
    const float* Wl    = (const float*)d_in[5];   // (18,100)
    const float* bl    = (const float*)d_in[6];   // (18,)
    const float* Wd    = (const float*)d_in[7];   // (100,18)
    const float* bd    = (const float*)d_in[8];   // (100,)

    float* out   = (float*)d_out;
    float* qout  = out;                 // first 100*512 floats
    float* yout  = out + QN * BC;       // then 512*256*256 floats
    float* coef  = (float*)d_ws;        // 512*32 floats = 64 KB

    prep_kernel<<<BC, 128, 0, stream>>>(query, Wl, bl, Wd, bd, qout, coef);

    // 16 bands of 16 rows per image; 4 waves (bands) per block
    dim3 grid(HH / (RBAND * 4), 1, BC);
    fused_kernel<<<grid, 256, 0, stream>>>(value, coef, yout);
}

// Round 8
// 267.562 us; speedup vs baseline: 1.0112x; 1.0061x over previous
//
#include <hip/hip_runtime.h>
#include <math.h>

#define HH 256
#define WW 256
#define BC 512   // B*C = 8*64
#define QN 100
#define RBAND 16 // output rows per wave

typedef float f32x4 __attribute__((ext_vector_type(4)));

// ---------------------------------------------------------------------------
// Kernel 1: per-(b,c) 18x100 GEMM + q output + derived conv coefficients.
// coef layout per bc (stride 32 floats): [0..8]=former, [9..17]=wk,
// [18..26]=|wk|, [27..29]=column sums of wk (kept for layout compat).
// ---------------------------------------------------------------------------
__global__ __launch_bounds__(128) void prep_kernel(
    const float* __restrict__ query,   // (100, 8, 64) = (100, 512)
    const float* __restrict__ Wl,      // (18, 100)
    const float* __restrict__ bl,      // (18,)
    const float* __restrict__ Wd,      // (100, 18)
    const float* __restrict__ bd,      // (100,)
    float* __restrict__ qout,          // (100, 512) region of d_out
    float* __restrict__ coef)          // (512, 32) in d_ws
{
    const int bc = blockIdx.x;
    const int t  = threadIdx.x;
    __shared__ float qcol[QN];
    __shared__ float c18[18];

    if (t < QN) qcol[t] = query[t * BC + bc];
    __syncthreads();

    if (t < 18) {
        float acc = bl[t];
        const float* wrow = Wl + t * QN;
        #pragma unroll 4
        for (int qi = 0; qi < QN; ++qi) acc += qcol[qi] * wrow[qi];
        c18[t] = acc;
    }
    __syncthreads();

    if (t < QN) {
        float acc = bd[t];
        const float* wrow = Wd + t * 18;
        #pragma unroll
        for (int k = 0; k < 18; ++k) acc += c18[k] * wrow[k];
        qout[t * BC + bc] = acc;   // q.transpose(2,0,1) layout
    }

    if (t < 18) {
        coef[bc * 32 + t] = c18[t];                      // former / wk
    } else if (t < 27) {
        coef[bc * 32 + t] = fabsf(c18[t - 9]);           // |wk|
    } else if (t < 30) {
        int j = t - 27;
        coef[bc * 32 + t] = c18[9 + j] + c18[12 + j] + c18[15 + j]; // colsum
    }
}

// ---------------------------------------------------------------------------
// Kernel 2: LDS-free streaming stencil, PAIR-ROW processing.
// One wave64 spans the full 256-col image width (4 cols/lane); each wave
// streams a 16-row band, two rows per iteration:
//   - two independent COMPD chains + two independent OUTROW chains per pair
//     (doubles ILP at every dependency point vs one-row-at-a-time),
//   - 6 row-loads batched per pair -> one waitcnt window per 2 rows,
//   - 4 diff-halo shfls batched per pair.
// Row guards are HOISTED: interior bands (1..14, 87.5% of waves) run a
// guard-free straight-line body (round-7 post-mortem: per-row uniform
// guards fragment the scheduler's basic blocks; VALU duty pinned ~50%).
// Stores are nontemporal (yout never re-read; keeps L2 for value stream).
// Rings: v[4][6] rows (mod-4 slots, read-before-clobber ordering), d[4][6],
// yt2[2][4]; raw[2][6] = in-flight pair (issued one pair = 2 rows ahead).
// Algebraic fold: res - res_diff = sum_b wk[b]*(vd(h-1)-vd(h))
//                                + wk[6+b]*(vd(h+1)-vd(h)).
// ---------------------------------------------------------------------------
__global__ __launch_bounds__(256, 4) void fused_kernel(
    const float* __restrict__ value,   // (512, 256, 256)
    const float* __restrict__ coef,    // (512, 32)
    float* __restrict__ yout)          // (512, 256, 256) region of d_out
{
    const int bc   = blockIdx.z;
    const int wave = threadIdx.x >> 6;
    const int lane = threadIdx.x & 63;
    const int band = blockIdx.x * 4 + wave;
    const int r0   = band * RBAND;
    const int x4   = lane << 2;

    const bool l0  = (lane == 0);
    const bool l63 = (lane == 63);
    // clamped halo columns (in-row; masked to 0 at FINISH)
    const int xl = l0  ? 0   : x4 - 1;
    const int xr = l63 ? 255 : x4 + 4;

    // coefficients: block-uniform address -> scalar (SGPR) loads
    const float* cp = coef + bc * 32;
    float fco[9], awk[9], wk6[6];
    #pragma unroll
    for (int i = 0; i < 9; ++i) { fco[i] = cp[i]; awk[i] = cp[18 + i]; }
    wk6[0] = cp[9];  wk6[1] = cp[10]; wk6[2] = cp[11];
    wk6[3] = cp[15]; wk6[4] = cp[16]; wk6[5] = cp[17];

    const float* vbase = value + (size_t)bc * (HH * WW);
    float*       obase = yout  + (size_t)bc * (HH * WW);

    float v[4][6];      // value rows, slot = row & 3, cols x4-1 .. x4+4
    float raw[2][6];    // in-flight pair
    float d[4][6];      // diff rows, slot = row & 3, cols x4-1 .. x4+4
    float yt2[2][4];    // former-conv reuse, slot = row & 1

    // tree-form 9-term dot: 3 independent 3-FMA chains, then 2 adds
    auto DOT9 = [](const float* f, const float* ra, const float* rb,
                   const float* rc, int c) -> float {
        float s0 = fmaf(f[2], ra[c + 2], fmaf(f[1], ra[c + 1], f[0] * ra[c]));
        float s1 = fmaf(f[5], rb[c + 2], fmaf(f[4], rb[c + 1], f[3] * rb[c]));
        float s2 = fmaf(f[8], rc[c + 2], fmaf(f[7], rc[c + 1], f[6] * rc[c]));
        return (s0 + s1) + s2;
    };

    // issue row r's loads into rw; chk=false -> unconditional (interior band)
    auto ISSUE = [&](int r, float* rw, bool chk) {
        if (!chk || (unsigned)r < HH) {
            const float* rowp = vbase + r * WW;
            const float4 q = *(const float4*)(rowp + x4);
            rw[0] = rowp[xl];
            rw[1] = q.x; rw[2] = q.y; rw[3] = q.z; rw[4] = q.w;
            rw[5] = rowp[xr];
        } else {
            #pragma unroll
            for (int m = 0; m < 6; ++m) rw[m] = 0.f;
        }
    };

    // edge-mask a raw buffer and retire it into a finished v row
    auto FINISH = [&](const float* rw, float* vr) {
        vr[0] = l0 ? 0.f : rw[0];
        vr[1] = rw[1]; vr[2] = rw[2]; vr[3] = rw[3]; vr[4] = rw[4];
        vr[5] = l63 ? 0.f : rw[5];
    };

    // prologue row load (issue + finish immediately)
    auto LOADV = [&](int r, float* vr) {
        float tmp[6];
        ISSUE(r, tmp, true);
        FINISH(tmp, vr);
    };

    // diff row r from value rows r-1 (va), r (vb), r+1 (vc); saves yt(r)
    auto COMPD = [&](int r, const float* va, const float* vb, const float* vc,
                     float* drow, float* ytr, bool chk) {
        if (!chk || (unsigned)r < HH) {
            float d4[4];
            #pragma unroll
            for (int c = 0; c < 4; ++c) {
                float yt = DOT9(fco, va, vb, vc, c);
                ytr[c] = yt;
                float e = vb[c + 1] - yt;
                d4[c] = __expf(-e * e);
            }
            drow[1] = d4[0]; drow[2] = d4[1]; drow[3] = d4[2]; drow[4] = d4[3];
            float left  = __shfl_up(d4[3], 1);
            float right = __shfl_down(d4[0], 1);
            drow[0] = l0  ? 0.f : left;
            drow[5] = l63 ? 0.f : right;
        } else {
            #pragma unroll
            for (int m = 0; m < 6; ++m) drow[m] = 0.f;
        }
    };

    // output row h (always in-image); yt(h) precomputed by COMPD(h)
    auto OUTROW = [&](int h, const float* vp, const float* vq, const float* vs,
                      const float* dp, const float* dq, const float* ds,
                      const float* ytr) {
        float dv0[6], dv2[6];
        #pragma unroll
        for (int m = 0; m < 6; ++m) {
            float mid = dq[m] * vq[m];
            dv0[m] = fmaf(dp[m], vp[m], -mid);
            dv2[m] = fmaf(ds[m], vs[m], -mid);
        }
        f32x4 o;
        #pragma unroll
        for (int c = 0; c < 4; ++c) {
            float y0 = fmaf(awk[2], dp[c + 2],
                       fmaf(awk[1], dp[c + 1], fmaf(awk[0], dp[c], 1e-10f)));
            float y1 = fmaf(awk[5], dq[c + 2],
                       fmaf(awk[4], dq[c + 1], awk[3] * dq[c]));
            float y2 = fmaf(awk[8], ds[c + 2],
                       fmaf(awk[7], ds[c + 1], awk[6] * ds[c]));
            float yd9 = (y0 + y1) + y2;
            float n0 = fmaf(wk6[2], dv0[c + 2],
                       fmaf(wk6[1], dv0[c + 1], wk6[0] * dv0[c]));
            float n1 = fmaf(wk6[5], dv2[c + 2],
                       fmaf(wk6[4], dv2[c + 1], wk6[3] * dv2[c]));
            float num = n0 + n1;
            o[c] = fmaf(-num, __builtin_amdgcn_rcpf(yd9), ytr[c]);
        }
        __builtin_nontemporal_store(o, (f32x4*)(obase + h * WW + x4));
    };

    // ---- prologue: rows r0-2..r0+1 finished (slots row&3); diff r0-1, r0;
    //      pair (r0+2, r0+3) in flight ----
    LOADV(r0 - 2, v[2]);
    LOADV(r0 - 1, v[3]);
    LOADV(r0,     v[0]);
    LOADV(r0 + 1, v[1]);
    COMPD(r0 - 1, v[2], v[3], v[0], d[3], yt2[1], true);
    COMPD(r0,     v[3], v[0], v[1], d[0], yt2[0], true);
    ISSUE(r0 + 2, raw[0], true);
    ISSUE(r0 + 3, raw[1], true);

    // ---- pair body: h = r0+4t+2u, s = h&3 = 2u.
    // Order is read-before-clobber: OUTROW(h) reads v/d slot (s+3)&3 (row
    // h-1) BEFORE raw[1] retires row h+3 into that v slot, and reads yt2[0]
    // (yt(h)) BEFORE COMPD(h+2) overwrites it.
    auto BODY = [&](int t, bool chk) {
        #pragma unroll
        for (int u = 0; u < 2; ++u) {
            const int s = 2 * u;
            const int h = r0 + 4 * t + s;
            FINISH(raw[0], v[(s + 2) & 3]);                   // row h+2
            COMPD(h + 1, v[s], v[(s + 1) & 3], v[(s + 2) & 3],
                  d[(s + 1) & 3], yt2[1], chk);
            OUTROW(h, v[(s + 3) & 3], v[s], v[(s + 1) & 3],
                   d[(s + 3) & 3], d[s], d[(s + 1) & 3], yt2[0]);
            FINISH(raw[1], v[(s + 3) & 3]);                   // row h+3
            if (4 * t + s < RBAND - 2) {                      // skip last pair
                ISSUE(h + 4, raw[0], chk);
                ISSUE(h + 5, raw[1], chk);
            }
            COMPD(h + 2, v[(s + 1) & 3], v[(s + 2) & 3], v[(s + 3) & 3],
                  d[(s + 2) & 3], yt2[0], chk);
            OUTROW(h + 1, v[s], v[(s + 1) & 3], v[(s + 2) & 3],
                   d[s], d[(s + 1) & 3], d[(s + 2) & 3], yt2[1]);
        }
    };

    if (r0 >= 2 && r0 + RBAND + 2 <= HH) {
        // interior bands: guard-free straight-line body
        for (int t = 0; t < RBAND / 4; ++t) BODY(t, false);
    } else {
        // first/last band: row-guarded body
        for (int t = 0; t < RBAND / 4; ++t) BODY(t, true);
    }
}

// ---------------------------------------------------------------------------
extern "C" void kernel_launch(void* const* d_in, const int* in_sizes, int n_in,
                              void* d_out, int out_size, void* d_ws, size_t ws_size,
                              hipStream_t stream) {
    const float* query = (const float*)d_in[0];   // (100,8,64)
    const float* value = (const float*)d_in[1];   // (8,64,256,256)
    // d_in[2..4]: unused scalars
    const float* Wl    = (const float*)d_in[5];   // (18,100)
    const float* bl    = (const float*)d_in[6];   // (18,)
    const float* Wd    = (const float*)d_in[7];   // (100,18)
    const float* bd    = (const float*)d_in[8];   // (100,)

    float* out   = (float*)d_out;
    float* qout  = out;                 // first 100*512 floats
    float* yout  = out + QN * BC;       // then 512*256*256 floats
    float* coef  = (float*)d_ws;        // 512*32 floats = 64 KB

    prep_kernel<<<BC, 128, 0, stream>>>(query, Wl, bl, Wd, bd, qout, coef);

    // 16 bands of 16 rows per image; 4 waves (bands) per block
    dim3 grid(HH / (RBAND * 4), 1, BC);
    fused_kernel<<<grid, 256, 0, stream>>>(value, coef, yout);
}